// Round 23
// baseline (54.645 us; speedup 1.0000x reference)
//
#include <hip/hip_runtime.h>
#include <hip/hip_bf16.h>
#include <math.h>
#include <string.h>

// out[n,:] = s1 .* FWHT( (u/4096) .* FWHT( s2 .* x[n,:] ) ),
// u = g_mu + softplus(g_rho)*epsilon, FWHT = unnormalized Walsh-Hadamard.
//
// R23 = R22 (best: 52.55 us = R17 MFMA formulation + non-temporal out
// stores; absmax 0.125) with the bf16 pack switched from 8-op integer RNE
// emulation to the HW packed conversion v_cvt_pk_bf16_f32 via HIP's
// __float22bfloat162_rn (compiler-visible -- NO inline asm, which NaN'd in
// R14). Bits extracted with memcpy (legal for the non-trivially-copyable
// HIP type; folds to a register mov). RNE identical -> absmax must stay
// exactly 0.125. Cuts ~1400 serial-chain VALU cycles per wave (the largest
// remaining compute term; VALUBusy 18%).
//
// Structure recap: D = 4096 digits (a,b,c), memory e = a*256 + c*16 + b.
// One wave per row: 16 register tiles (a) of 16x16 (b,c); lane l holds
// T[4*(l>>4)+r][l&15]. mfma_f32_16x16x32_bf16 with B = H16-fragment performs
// T -> (H*T)^T (output layout == input layout); two chained stages = H*T*H.
// a-axis = in-register pk-FWHT16 (f32). All global I/O: one b128 per tile
// per lane, addr = base + a*256 + (l&15)*16 + (l>>4)*4. u natural order.
// Non-temporal stores keep out-lines out of L2/L3 (R22's +16%).

#define WHVI_D 4096

typedef float f2 __attribute__((ext_vector_type(2)));
typedef float f32x4 __attribute__((ext_vector_type(4)));
typedef short bf16x8 __attribute__((ext_vector_type(8)));  // 8 bf16 = 4 VGPRs

__global__ __launch_bounds__(256)
void u_precompute_kernel(const float* __restrict__ g_mu,
                         const float* __restrict__ g_rho,
                         const float* __restrict__ g_eps,
                         float* __restrict__ u) {
    int k = blockIdx.x * 256 + threadIdx.x;  // 0..4095
    float rho = g_rho[k];
    float sp = fmaxf(rho, 0.0f) + __logf(1.0f + __expf(-fabsf(rho)));
    u[k] = (g_mu[k] + sp * g_eps[k]) * (1.0f / 4096.0f);  // natural order
}

// fp32 pair -> packed bf16x2 dword via the HW cvt (RNE, same rounding as
// the R13-R22 integer emulation -> bit-identical results).
__device__ __forceinline__ unsigned pack_bf(float a, float b) {
    __hip_bfloat162 h2 = __float22bfloat162_rn(float2{a, b});
    unsigned w;
    memcpy(&w, &h2, 4);
    return w;
}

// One transform stage on a packed tile: A = packed bf16 frag (j<4 slots),
// D = A*B_H contracts the hi axis and swaps axes (layout-preserving).
__device__ __forceinline__ f32x4 stage_mfma(uint2 in, bf16x8 Bfrag) {
    uint4 ab;
    ab.x = in.x;
    ab.y = in.y;
    ab.z = 0u;
    ab.w = 0u;
    bf16x8 A = __builtin_bit_cast(bf16x8, ab);
    return __builtin_amdgcn_mfma_f32_16x16x32_bf16(
        A, Bfrag, (f32x4){0.f, 0.f, 0.f, 0.f}, 0, 0, 0);
}

__global__ __launch_bounds__(256, 4)
void whvi_mfma_kernel(const float* __restrict__ x,
                      const float* __restrict__ s1,
                      const float* __restrict__ s2,
                      const float* __restrict__ u,
                      float* __restrict__ out,
                      int nrows) {
    const int t = threadIdx.x;
    const int l = t & 63;                 // lane
    const int row = blockIdx.x * 4 + (t >> 6);
    if (row >= nrows) return;

    const int lo = l & 15;                // tile column slot
    const int g4 = (l >> 4) << 2;         // tile row base (row = g4 + r)
    const int laneoff = lo * 16 + (l >> 4) * 4;
    const size_t base = (size_t)row * WHVI_D + laneoff;

    // ---- H16 fragment as B-operand (constant, +-1 exact in bf16) ----
    uint4 hbits;
    {
        unsigned s0 = (__popc((g4 + 0) & lo) & 1) ? 0xBF80u : 0x3F80u;
        unsigned s1b = (__popc((g4 + 1) & lo) & 1) ? 0xBF80u : 0x3F80u;
        unsigned s2b = (__popc((g4 + 2) & lo) & 1) ? 0xBF80u : 0x3F80u;
        unsigned s3 = (__popc((g4 + 3) & lo) & 1) ? 0xBF80u : 0x3F80u;
        hbits.x = s0 | (s1b << 16);
        hbits.y = s2b | (s3 << 16);
        hbits.z = 0u;
        hbits.w = 0u;
    }
    const bf16x8 Bfrag = __builtin_bit_cast(bf16x8, hbits);

    uint2 db[16];  // packed bf16 tiles (2 regs each)

    // ---- load x, scale s2, pack (quantization event #1) ----
#pragma unroll
    for (int a = 0; a < 16; ++a) {
        float4 v = *reinterpret_cast<const float4*>(x + base + a * 256);
        float4 s = *reinterpret_cast<const float4*>(s2 + laneoff + a * 256);
        db[a].x = pack_bf(v.x * s.x, v.y * s.y);
        db[a].y = pack_bf(v.z * s.z, v.w * s.w);
    }

    // ---- stage 1 (b-axis): packed -> packed (event #2) ----
#pragma unroll
    for (int a = 0; a < 16; ++a) {
        f32x4 Dv = stage_mfma(db[a], Bfrag);
        db[a].x = pack_bf(Dv[0], Dv[1]);
        db[a].y = pack_bf(Dv[2], Dv[3]);
    }

    // ---- stage 2 (c-axis): packed -> f32 (db dies as d grows) ----
    f2 d[16][2];
#pragma unroll
    for (int a = 0; a < 16; ++a) {
        f32x4 Dv = stage_mfma(db[a], Bfrag);
        d[a][0] = f2{Dv[0], Dv[1]};
        d[a][1] = f2{Dv[2], Dv[3]};
    }

    // ---- a-axis FWHT16 (exact f32, pk ops) ----
#define AFWHT()                                                              \
    do {                                                                     \
        _Pragma("unroll") for (int s = 1; s < 16; s <<= 1) {                 \
            _Pragma("unroll") for (int a = 0; a < 16; ++a) {                 \
                if ((a & s) == 0) {                                          \
                    _Pragma("unroll") for (int p = 0; p < 2; ++p) {          \
                        f2 A = d[a][p], B = d[a | s][p];                     \
                        d[a][p] = A + B;                                     \
                        d[a | s][p] = A - B;                                 \
                    }                                                        \
                }                                                            \
            }                                                                \
        }                                                                    \
    } while (0)

    AFWHT();

    // ---- diagonal u (natural order, exact f32) ----
#pragma unroll
    for (int a = 0; a < 16; ++a) {
        float4 uu = *reinterpret_cast<const float4*>(u + laneoff + a * 256);
        d[a][0] *= f2{uu.x, uu.y};
        d[a][1] *= f2{uu.z, uu.w};
    }

    AFWHT();
#undef AFWHT

    // ---- pack for stage 3 (event #3; d dies as db grows) ----
#pragma unroll
    for (int a = 0; a < 16; ++a) {
        db[a].x = pack_bf(d[a][0].x, d[a][0].y);
        db[a].y = pack_bf(d[a][1].x, d[a][1].y);
    }

    // ---- stage 3 (b-axis): packed -> packed (event #4) ----
#pragma unroll
    for (int a = 0; a < 16; ++a) {
        f32x4 Dv = stage_mfma(db[a], Bfrag);
        db[a].x = pack_bf(Dv[0], Dv[1]);
        db[a].y = pack_bf(Dv[2], Dv[3]);
    }

    // ---- stage 4 (c-axis) + s1 scale + NON-TEMPORAL store, per-tile ----
#pragma unroll
    for (int a = 0; a < 16; ++a) {
        f32x4 Dv = stage_mfma(db[a], Bfrag);
        float4 s = *reinterpret_cast<const float4*>(s1 + laneoff + a * 256);
        f32x4 o;
        o[0] = Dv[0] * s.x;
        o[1] = Dv[1] * s.y;
        o[2] = Dv[2] * s.z;
        o[3] = Dv[3] * s.w;
        __builtin_nontemporal_store(
            o, reinterpret_cast<f32x4*>(out + base + a * 256));
    }
}

extern "C" void kernel_launch(void* const* d_in, const int* in_sizes, int n_in,
                              void* d_out, int out_size, void* d_ws, size_t ws_size,
                              hipStream_t stream) {
    const float* x     = (const float*)d_in[0];
    const float* s1    = (const float*)d_in[1];
    const float* s2    = (const float*)d_in[2];
    const float* g_mu  = (const float*)d_in[3];
    const float* g_rho = (const float*)d_in[4];
    const float* g_eps = (const float*)d_in[5];
    // d_in[6] is H — unused; the FWHT realizes it exactly.
    float* out = (float*)d_out;

    const int nrows = in_sizes[0] / WHVI_D;  // 8192

    float* u = (float*)d_ws;  // 16 KB workspace
    u_precompute_kernel<<<WHVI_D / 256, 256, 0, stream>>>(g_mu, g_rho, g_eps, u);

    const int nblk = (nrows + 3) / 4;
    whvi_mfma_kernel<<<nblk, 256, 0, stream>>>(x, s1, s2, u, out, nrows);
}

// Round 24
// 52.138 us; speedup vs baseline: 1.0481x; 1.0481x over previous
//
#include <hip/hip_runtime.h>
#include <hip/hip_bf16.h>
#include <math.h>

// out[n,:] = s1 .* FWHT( (u/4096) .* FWHT( s2 .* x[n,:] ) ),
// u = g_mu + softplus(g_rho)*epsilon, FWHT = unnormalized Walsh-Hadamard.
//
// R24 = byte-exact revert to R22 (session best: 52.55 us). R23's HW-cvt
// pack regressed (54.65 us, VALUBusy unchanged, +8 MB WRITE) -> discarded.
// R22 = R17 MFMA formulation + non-temporal out stores:
//  - MFMA realizes the b/c-axis H16 transforms (zero LDS, zero cross-lane)
//  - integer-RNE bf16 pack (proven bit-exact across R13-R22, absmax 0.125)
//  - nt stores keep out-lines out of L2/L3 (+16%: 62.65 -> 52.55 us)
//
// Structure: D = 4096 digits (a,b,c), memory e = a*256 + c*16 + b.
// One wave per row: 16 register tiles (a) of 16x16 (b,c); lane l holds
// T[4*(l>>4)+r][l&15]. mfma_f32_16x16x32_bf16 with B = H16-fragment performs
// T -> (H*T)^T (output layout == input layout); two chained stages = H*T*H.
// a-axis = in-register pk-FWHT16 (f32). All global I/O: one b128 per tile
// per lane, addr = base + a*256 + (l&15)*16 + (l>>4)*4. u natural order.

#define WHVI_D 4096

typedef float f2 __attribute__((ext_vector_type(2)));
typedef float f32x4 __attribute__((ext_vector_type(4)));
typedef short bf16x8 __attribute__((ext_vector_type(8)));  // 8 bf16 = 4 VGPRs

__global__ __launch_bounds__(256)
void u_precompute_kernel(const float* __restrict__ g_mu,
                         const float* __restrict__ g_rho,
                         const float* __restrict__ g_eps,
                         float* __restrict__ u) {
    int k = blockIdx.x * 256 + threadIdx.x;  // 0..4095
    float rho = g_rho[k];
    float sp = fmaxf(rho, 0.0f) + __logf(1.0f + __expf(-fabsf(rho)));
    u[k] = (g_mu[k] + sp * g_eps[k]) * (1.0f / 4096.0f);  // natural order
}

// fp32 -> bf16 bits, round-to-nearest-even (pure integer, R13/R15-proven).
__device__ __forceinline__ unsigned bf16_bits(float f) {
    unsigned uu = __builtin_bit_cast(unsigned, f);
    unsigned r = 0x7FFFu + ((uu >> 16) & 1u);
    return (uu + r) >> 16;
}
__device__ __forceinline__ unsigned pack_bf(float a, float b) {
    return bf16_bits(a) | (bf16_bits(b) << 16);
}

// One transform stage on a packed tile: A = packed bf16 frag (j<4 slots),
// D = A*B_H contracts the hi axis and swaps axes (layout-preserving).
__device__ __forceinline__ f32x4 stage_mfma(uint2 in, bf16x8 Bfrag) {
    uint4 ab;
    ab.x = in.x;
    ab.y = in.y;
    ab.z = 0u;
    ab.w = 0u;
    bf16x8 A = __builtin_bit_cast(bf16x8, ab);
    return __builtin_amdgcn_mfma_f32_16x16x32_bf16(
        A, Bfrag, (f32x4){0.f, 0.f, 0.f, 0.f}, 0, 0, 0);
}

__global__ __launch_bounds__(256, 4)
void whvi_mfma_kernel(const float* __restrict__ x,
                      const float* __restrict__ s1,
                      const float* __restrict__ s2,
                      const float* __restrict__ u,
                      float* __restrict__ out,
                      int nrows) {
    const int t = threadIdx.x;
    const int l = t & 63;                 // lane
    const int row = blockIdx.x * 4 + (t >> 6);
    if (row >= nrows) return;

    const int lo = l & 15;                // tile column slot
    const int g4 = (l >> 4) << 2;         // tile row base (row = g4 + r)
    const int laneoff = lo * 16 + (l >> 4) * 4;
    const size_t base = (size_t)row * WHVI_D + laneoff;

    // ---- H16 fragment as B-operand (constant, +-1 exact in bf16) ----
    uint4 hbits;
    {
        unsigned s0 = (__popc((g4 + 0) & lo) & 1) ? 0xBF80u : 0x3F80u;
        unsigned s1b = (__popc((g4 + 1) & lo) & 1) ? 0xBF80u : 0x3F80u;
        unsigned s2b = (__popc((g4 + 2) & lo) & 1) ? 0xBF80u : 0x3F80u;
        unsigned s3 = (__popc((g4 + 3) & lo) & 1) ? 0xBF80u : 0x3F80u;
        hbits.x = s0 | (s1b << 16);
        hbits.y = s2b | (s3 << 16);
        hbits.z = 0u;
        hbits.w = 0u;
    }
    const bf16x8 Bfrag = __builtin_bit_cast(bf16x8, hbits);

    uint2 db[16];  // packed bf16 tiles (2 regs each)

    // ---- load x, scale s2, pack (quantization event #1) ----
#pragma unroll
    for (int a = 0; a < 16; ++a) {
        float4 v = *reinterpret_cast<const float4*>(x + base + a * 256);
        float4 s = *reinterpret_cast<const float4*>(s2 + laneoff + a * 256);
        db[a].x = pack_bf(v.x * s.x, v.y * s.y);
        db[a].y = pack_bf(v.z * s.z, v.w * s.w);
    }

    // ---- stage 1 (b-axis): packed -> packed (event #2) ----
#pragma unroll
    for (int a = 0; a < 16; ++a) {
        f32x4 Dv = stage_mfma(db[a], Bfrag);
        db[a].x = pack_bf(Dv[0], Dv[1]);
        db[a].y = pack_bf(Dv[2], Dv[3]);
    }

    // ---- stage 2 (c-axis): packed -> f32 (db dies as d grows) ----
    f2 d[16][2];
#pragma unroll
    for (int a = 0; a < 16; ++a) {
        f32x4 Dv = stage_mfma(db[a], Bfrag);
        d[a][0] = f2{Dv[0], Dv[1]};
        d[a][1] = f2{Dv[2], Dv[3]};
    }

    // ---- a-axis FWHT16 (exact f32, pk ops) ----
#define AFWHT()                                                              \
    do {                                                                     \
        _Pragma("unroll") for (int s = 1; s < 16; s <<= 1) {                 \
            _Pragma("unroll") for (int a = 0; a < 16; ++a) {                 \
                if ((a & s) == 0) {                                          \
                    _Pragma("unroll") for (int p = 0; p < 2; ++p) {          \
                        f2 A = d[a][p], B = d[a | s][p];                     \
                        d[a][p] = A + B;                                     \
                        d[a | s][p] = A - B;                                 \
                    }                                                        \
                }                                                            \
            }                                                                \
        }                                                                    \
    } while (0)

    AFWHT();

    // ---- diagonal u (natural order, exact f32) ----
#pragma unroll
    for (int a = 0; a < 16; ++a) {
        float4 uu = *reinterpret_cast<const float4*>(u + laneoff + a * 256);
        d[a][0] *= f2{uu.x, uu.y};
        d[a][1] *= f2{uu.z, uu.w};
    }

    AFWHT();
#undef AFWHT

    // ---- pack for stage 3 (event #3; d dies as db grows) ----
#pragma unroll
    for (int a = 0; a < 16; ++a) {
        db[a].x = pack_bf(d[a][0].x, d[a][0].y);
        db[a].y = pack_bf(d[a][1].x, d[a][1].y);
    }

    // ---- stage 3 (b-axis): packed -> packed (event #4) ----
#pragma unroll
    for (int a = 0; a < 16; ++a) {
        f32x4 Dv = stage_mfma(db[a], Bfrag);
        db[a].x = pack_bf(Dv[0], Dv[1]);
        db[a].y = pack_bf(Dv[2], Dv[3]);
    }

    // ---- stage 4 (c-axis) + s1 scale + NON-TEMPORAL store, per-tile ----
#pragma unroll
    for (int a = 0; a < 16; ++a) {
        f32x4 Dv = stage_mfma(db[a], Bfrag);
        float4 s = *reinterpret_cast<const float4*>(s1 + laneoff + a * 256);
        f32x4 o;
        o[0] = Dv[0] * s.x;
        o[1] = Dv[1] * s.y;
        o[2] = Dv[2] * s.z;
        o[3] = Dv[3] * s.w;
        __builtin_nontemporal_store(
            o, reinterpret_cast<f32x4*>(out + base + a * 256));
    }
}

extern "C" void kernel_launch(void* const* d_in, const int* in_sizes, int n_in,
                              void* d_out, int out_size, void* d_ws, size_t ws_size,
                              hipStream_t stream) {
    const float* x     = (const float*)d_in[0];
    const float* s1    = (const float*)d_in[1];
    const float* s2    = (const float*)d_in[2];
    const float* g_mu  = (const float*)d_in[3];
    const float* g_rho = (const float*)d_in[4];
    const float* g_eps = (const float*)d_in[5];
    // d_in[6] is H — unused; the FWHT realizes it exactly.
    float* out = (float*)d_out;

    const int nrows = in_sizes[0] / WHVI_D;  // 8192

    float* u = (float*)d_ws;  // 16 KB workspace
    u_precompute_kernel<<<WHVI_D / 256, 256, 0, stream>>>(g_mu, g_rho, g_eps, u);

    const int nblk = (nrows + 3) / 4;
    whvi_mfma_kernel<<<nblk, 256, 0, stream>>>(x, s1, s2, u, out, nrows);
}